// Round 9
// baseline (218.034 us; speedup 1.0000x reference)
//
#include <hip/hip_runtime.h>
#include <stdint.h>

// 3-layer binary net as XNOR-popcount on bit-packed vectors.
// ws: X1p 65536*32 u32 @0 (8MB) | cA 256*1024 s8 | cB 256*1024 u8 |
//     M1p 1024*32 u32 | M2p 24*32 u32 | X2p 65536*32 u32 (8MB)
#define WS_CA  8388608
#define WS_CB  8650752
#define WS_M1  8912896
#define WS_M2  9043968
#define WS_X2  9047040

// async global->LDS, 16B per lane; LDS base must be wave-uniform (HW writes
// lane i at base + i*16). Swizzled layouts achieved by swizzling the SOURCE.
__device__ __forceinline__ void stage16(const uint4* g, uint4* l) {
  __builtin_amdgcn_global_load_lds((const __attribute__((address_space(1))) void*)g,
                                   (__attribute__((address_space(3))) void*)l, 16, 0, 0);
}

// ---- mask upload-format sniffing (bool arrays may arrive as u8, i32, or f32) ----
__device__ inline int detect_mode(const unsigned char* p) {
  unsigned nonalign = 0;
  for (int i = 0; i < 64; i++)
    if (i & 3) nonalign |= p[i];
  if (nonalign == 0) return 1;                 // int32 0/1
  bool f32ok = true;
  for (int e = 0; e < 16; e++) {
    const unsigned char* q = p + 4 * e;
    bool one  = (q[0] == 0 && q[1] == 0 && q[2] == 0x80 && q[3] == 0x3F);
    bool zero = (q[0] == 0 && q[1] == 0 && q[2] == 0 && q[3] == 0);
    if (!(one || zero)) { f32ok = false; break; }
  }
  return f32ok ? 2 : 0;
}

__device__ inline int maskbit(const unsigned char* p, int idx, int mode) {
  if (mode == 1) return ((const int*)p)[idx] & 1;
  if (mode == 2) return ((const float*)p)[idx] != 0.0f;
  return p[idx] & 1;
}

__global__ __launch_bounds__(256) void prep_kernel(
    const unsigned char* __restrict__ mask0, const int* __restrict__ thr0,
    const unsigned char* __restrict__ mask1, const unsigned char* __restrict__ mask2,
    signed char* __restrict__ cA, unsigned char* __restrict__ cB,
    unsigned* __restrict__ M1p, unsigned* __restrict__ M2p) {
  __shared__ int smode;
  if (threadIdx.x == 0) smode = detect_mode(mask1);   // one sniff per block
  __syncthreads();
  int mode = smode;
  int gid = blockIdx.x * 256 + threadIdx.x;
  if (gid < 524288) {              // cA / cB tables
    int which = gid >> 18;         // 0 = cA (h-bits), 1 = cB (w-bits)
    int idx = gid & 262143;
    int hw = idx >> 10;
    int o  = idx & 1023;
    int base = which ? 8 : 0;
    int cnt = 0;
#pragma unroll
    for (int i = 0; i < 8; i++) {
      int xb = (hw >> (7 - i)) & 1;                     // MSB-first bits
      int mb = maskbit(mask0, (base + i) * 1024 + o, mode);
      cnt += (xb == mb);
    }
    if (which) cB[idx] = (unsigned char)cnt;
    else       cA[idx] = (signed char)(cnt - thr0[o]);  // fold threshold in
    return;
  }
  int g2 = gid - 524288;
  if (g2 < 32768) {                // pack mask1: M1p[o][kw]; LSB-first bits
    int kw = g2 >> 10, o = g2 & 1023;
    unsigned wv = 0;
#pragma unroll
    for (int b = 0; b < 32; b++)
      wv |= (unsigned)maskbit(mask1, (kw * 32 + b) * 1024 + o, mode) << b;
    M1p[o * 32 + kw] = wv;
    return;
  }
  int g3 = g2 - 32768;
  if (g3 < 768) {                  // pack mask2: M2p[o][kw]
    int kw = g3 / 24, o = g3 % 24;
    unsigned wv = 0;
    for (int b = 0; b < 32; b++)
      wv |= (unsigned)maskbit(mask2, (kw * 32 + b) * 24 + o, mode) << b;
    M2p[o * 32 + kw] = wv;
  }
}

// Layer-0 evaluate + bit-pack. R2-style massively-parallel: 1 pixel per block
// (65536 blocks). R6-R8's fewer-blocks "optimization" correlated with aux time
// growing 44->69us; revert to the proven config.
__global__ __launch_bounds__(256) void pack_x1(
    const signed char* __restrict__ cA, const unsigned char* __restrict__ cB,
    unsigned* __restrict__ X1p) {
  int t = threadIdx.x;
  int lane = t & 63;
  int q = t >> 6;                  // wave id in block
  int n = blockIdx.x;
  int h = n >> 8, w = n & 255;
  const signed char*   ca = cA + h * 1024;
  const unsigned char* cb = cB + w * 1024;
#pragma unroll
  for (int j = 0; j < 4; j++) {
    int o = q * 256 + j * 64 + lane;
    bool bit = ((int)ca[o] + (int)cb[o]) > 0;          // cA+cB > thr0
    unsigned long long bal = __ballot(bit);
    if (lane == 0) {
      uint2 v; v.x = (unsigned)bal; v.y = (unsigned)(bal >> 32);
      *reinterpret_cast<uint2*>(&X1p[n * 32 + q * 8 + 2 * j]) = v;
    }
  }
}

// Main: L1 popcount-GEMM. Block = 128px x 512out, grid 1024 (4 blocks/CU).
// Core: per-thread 8x8 acc, kq real loop (#pragma unroll 1), VGPR <= 128.
// R9: async global_load_lds staging (no VGPR transients; XOR swizzle applied
// to the SOURCE address, LDS destination linear) + software pipeline: the
// next M-tile's loads are issued right after the compute barrier and land
// while the threshold/pack phase runs -> L2 latency hidden. oc order is
// staggered by (pb&3) to desync co-resident blocks.
__global__ __launch_bounds__(256) void main_kernel(
    const uint4* __restrict__ X1p4, const uint4* __restrict__ M1p4,
    const int* __restrict__ thr1, unsigned* __restrict__ X2p) {
  __shared__ uint4 lx4[1024];      // 16 KB  X tile  [row][kq^(row&7)]
  __shared__ uint4 lm4[1024];      // 16 KB  M tile (rewritten per oc)
  int t = threadIdx.x;
  int pb = blockIdx.x >> 1;        // pixel-block 0..511
  int half = blockIdx.x & 1;       // output half
  int n0 = pb << 7;
  int wb = (t >> 6) << 6;          // wave base within a 256-element quarter

  // swizzled source index: element L of the linear LDS tile comes from
  // row = L>>3, kq = (L&7)^(row&7)  ->  src = (L&~7) | ((L&7)^((L>>3)&7))
#pragma unroll
  for (int i = 0; i < 4; i++) {
    int L = t + (i << 8);
    int src = (L & ~7) | ((L & 7) ^ ((L >> 3) & 7));
    stage16(&X1p4[(n0 << 3) + src], &lx4[(i << 8) + wb]);
  }
  int oc0 = half * 4 + ((pb & 3) & 3);   // staggered first chunk
  {
    int oc = half * 4 + ((0 + (pb & 3)) & 3);
#pragma unroll
    for (int i = 0; i < 4; i++) {
      int L = t + (i << 8);
      int src = (oc << 10) | (L & ~7) | ((L & 7) ^ ((L >> 3) & 7));
      stage16(&M1p4[src], &lm4[(i << 8) + wb]);
    }
  }

  int oc_t = t & 15;               // output-thread 0..15 (owns 8 outs, stride 16)
  int pr_t = t >> 4;               // pixel-thread 0..15 (owns 8 px, stride 16)
  int pgrp = pr_t & 3;             // pixel group within wave
  int sx = pr_t & 7;               // X-tile swizzle key (const per thread)
  int so = oc_t & 7;               // M-tile swizzle key

  __syncthreads();                 // drains vmcnt -> lx4 + first lm4 ready

  for (int oc4 = 0; oc4 < 4; oc4++) {
    int oc = half * 4 + ((oc4 + (pb & 3)) & 3);

    unsigned acc[8][8];
#pragma unroll
    for (int i = 0; i < 8; i++)
#pragma unroll
      for (int j = 0; j < 8; j++) acc[i][j] = 0;

#pragma unroll 1
    for (int kq = 0; kq < 8; kq++) {
      const uint4* xp = &lx4[(pr_t << 3) + (kq ^ sx)];
      const uint4* mp = &lm4[(oc_t << 3) + (kq ^ so)];
      uint4 xv[8];
#pragma unroll
      for (int i = 0; i < 8; i++) xv[i] = xp[i << 7];   // +2048B immediates
      uint4 mvn = mp[0];
#pragma unroll
      for (int j = 0; j < 8; j++) {
        uint4 mv = mvn;
        if (j < 7) mvn = mp[(j + 1) << 7];              // 1-deep prefetch
#pragma unroll
        for (int i = 0; i < 8; i++) {
          acc[i][j] += __popc(xv[i].x ^ mv.x);
          acc[i][j] += __popc(xv[i].y ^ mv.y);
          acc[i][j] += __popc(xv[i].z ^ mv.z);
          acc[i][j] += __popc(xv[i].w ^ mv.w);
        }
      }
    }

    __syncthreads();               // all waves done reading lm4

    if (oc4 < 3) {                 // issue next M-tile async; lands during pack
      int ocn = half * 4 + ((oc4 + 1 + (pb & 3)) & 3);
#pragma unroll
      for (int i = 0; i < 4; i++) {
        int L = t + (i << 8);
        int src = (ocn << 10) | (L & ~7) | ((L & 7) ^ ((L >> 3) & 7));
        stage16(&M1p4[src], &lm4[(i << 8) + wb]);
      }
    }

    // threshold + ballot-pack x2 bits -> global X2p (no lm4 access here)
    int limv[8];
#pragma unroll
    for (int j = 0; j < 8; j++)
      limv[j] = 1024 - thr1[(oc << 7) + (j << 4) + oc_t];
#pragma unroll
    for (int i = 0; i < 8; i++) {
      unsigned wacc[4] = {0, 0, 0, 0};
#pragma unroll
      for (int j = 0; j < 8; j++) {
        bool bit = ((int)acc[i][j]) < limv[j];          // 1024-acc > thr1
        unsigned long long bal = __ballot(bit);
        unsigned hw16 = (unsigned)(bal >> (pgrp << 4)) & 0xFFFFu;
        wacc[j >> 1] |= hw16 << ((j & 1) << 4);
      }
      if (oc_t == 0) {
        int n = n0 + pr_t + (i << 4);
        uint4 v; v.x = wacc[0]; v.y = wacc[1]; v.z = wacc[2]; v.w = wacc[3];
        *reinterpret_cast<uint4*>(&X2p[(unsigned)n * 32 + (oc << 2)]) = v;
      }
    }

    __syncthreads();               // drains vmcnt -> next lm4 ready
  }
  (void)oc0;
}

// Layer 2 + epilogue: 256 px/block, one px/thread.
__global__ __launch_bounds__(256) void l2_kernel(
    const uint4* __restrict__ X2p4, const unsigned* __restrict__ M2p,
    const int* __restrict__ thr2, const float* __restrict__ image,
    float* __restrict__ out) {
  __shared__ unsigned lm2[768];
  int t = threadIdx.x;
  for (int r = t; r < 768; r += 256) lm2[r] = M2p[r];
  __syncthreads();
  int n = blockIdx.x * 256 + t;
  uint4 xw[8];
#pragma unroll
  for (int q = 0; q < 8; q++) xw[q] = X2p4[(unsigned)n * 8 + q];
#pragma unroll
  for (int c = 0; c < 3; c++) {
    int val = 0;
#pragma unroll
    for (int b = 0; b < 8; b++) {
      int o = c * 8 + b;
      const unsigned* m = &lm2[o * 32];
      unsigned acc2 = 0;
#pragma unroll
      for (int q = 0; q < 8; q++) {
        acc2 += __popc(xw[q].x ^ m[q * 4 + 0]);
        acc2 += __popc(xw[q].y ^ m[q * 4 + 1]);
        acc2 += __popc(xw[q].z ^ m[q * 4 + 2]);
        acc2 += __popc(xw[q].w ^ m[q * 4 + 3]);
      }
      int bit = ((int)(1024u - acc2)) > thr2[o];
      val |= bit << (7 - b);                            // MSB-first
    }
    out[c * 65536 + n] = (float)val;
    out[196608 + c * 65536 + n] = (float)val - image[c * 65536 + n];
  }
}

extern "C" void kernel_launch(void* const* d_in, const int* in_sizes, int n_in,
                              void* d_out, int out_size, void* d_ws, size_t ws_size,
                              hipStream_t stream) {
  const float*         image = (const float*)d_in[0];
  const unsigned char* mask0 = (const unsigned char*)d_in[1];
  const int*           thr0  = (const int*)d_in[2];
  const unsigned char* mask1 = (const unsigned char*)d_in[3];
  const int*           thr1  = (const int*)d_in[4];
  const unsigned char* mask2 = (const unsigned char*)d_in[5];
  const int*           thr2  = (const int*)d_in[6];
  char* ws = (char*)d_ws;
  unsigned*      X1p = (unsigned*)(ws);
  signed char*   cA  = (signed char*)(ws + WS_CA);
  unsigned char* cB  = (unsigned char*)(ws + WS_CB);
  unsigned*      M1p = (unsigned*)(ws + WS_M1);
  unsigned*      M2p = (unsigned*)(ws + WS_M2);
  unsigned*      X2p = (unsigned*)(ws + WS_X2);
  float* out = (float*)d_out;

  hipLaunchKernelGGL(prep_kernel, dim3(2179), dim3(256), 0, stream,
                     mask0, thr0, mask1, mask2, cA, cB, M1p, M2p);
  hipLaunchKernelGGL(pack_x1, dim3(65536), dim3(256), 0, stream, cA, cB, X1p);
  hipLaunchKernelGGL(main_kernel, dim3(1024), dim3(256), 0, stream,
                     (const uint4*)X1p, (const uint4*)M1p, thr1, X2p);
  hipLaunchKernelGGL(l2_kernel, dim3(256), dim3(256), 0, stream,
                     (const uint4*)X2p, M2p, thr2, image, out);
}

// Round 10
// 213.311 us; speedup vs baseline: 1.0221x; 1.0221x over previous
//
#include <hip/hip_runtime.h>
#include <stdint.h>

// 3-layer binary net as XNOR-popcount on bit-packed vectors.
// ws: X1p 65536*32 u32 @0 (8MB) | cA 256*1024 s8 | cB 256*1024 u8 |
//     M1p 1024*32 u32 | M2p 24*32 u32 | X2p 65536*32 u32 (8MB)
#define WS_CA  8388608
#define WS_CB  8650752
#define WS_M1  8912896
#define WS_M2  9043968
#define WS_X2  9047040

// v_bcnt_u32_b32 dst, src, acc  ->  dst = popcount(src) + acc.
// Forcing the accumulate form: R10's hypothesis is that hipcc emits
// bcnt + separate v_add (3 ops/word instead of 2) for acc += __popc(x).
#define BCNT_ACC(a, x) asm("v_bcnt_u32_b32 %0, %1, %0" : "+v"(a) : "v"(x))

// async global->LDS, 16B per lane; LDS base must be wave-uniform.
__device__ __forceinline__ void stage16(const uint4* g, uint4* l) {
  __builtin_amdgcn_global_load_lds((const __attribute__((address_space(1))) void*)g,
                                   (__attribute__((address_space(3))) void*)l, 16, 0, 0);
}

// ---- mask upload-format sniffing (bool arrays may arrive as u8, i32, or f32) ----
__device__ inline int detect_mode(const unsigned char* p) {
  unsigned nonalign = 0;
  for (int i = 0; i < 64; i++)
    if (i & 3) nonalign |= p[i];
  if (nonalign == 0) return 1;                 // int32 0/1
  bool f32ok = true;
  for (int e = 0; e < 16; e++) {
    const unsigned char* q = p + 4 * e;
    bool one  = (q[0] == 0 && q[1] == 0 && q[2] == 0x80 && q[3] == 0x3F);
    bool zero = (q[0] == 0 && q[1] == 0 && q[2] == 0 && q[3] == 0);
    if (!(one || zero)) { f32ok = false; break; }
  }
  return f32ok ? 2 : 0;
}

__device__ inline int maskbit(const unsigned char* p, int idx, int mode) {
  if (mode == 1) return ((const int*)p)[idx] & 1;
  if (mode == 2) return ((const float*)p)[idx] != 0.0f;
  return p[idx] & 1;
}

__global__ __launch_bounds__(256) void prep_kernel(
    const unsigned char* __restrict__ mask0, const int* __restrict__ thr0,
    const unsigned char* __restrict__ mask1, const unsigned char* __restrict__ mask2,
    signed char* __restrict__ cA, unsigned char* __restrict__ cB,
    unsigned* __restrict__ M1p, unsigned* __restrict__ M2p) {
  __shared__ int smode;
  if (threadIdx.x == 0) smode = detect_mode(mask1);   // one sniff per block
  __syncthreads();
  int mode = smode;
  int gid = blockIdx.x * 256 + threadIdx.x;
  if (gid < 524288) {              // cA / cB tables
    int which = gid >> 18;         // 0 = cA (h-bits), 1 = cB (w-bits)
    int idx = gid & 262143;
    int hw = idx >> 10;
    int o  = idx & 1023;
    int base = which ? 8 : 0;
    int cnt = 0;
#pragma unroll
    for (int i = 0; i < 8; i++) {
      int xb = (hw >> (7 - i)) & 1;                     // MSB-first bits
      int mb = maskbit(mask0, (base + i) * 1024 + o, mode);
      cnt += (xb == mb);
    }
    if (which) cB[idx] = (unsigned char)cnt;
    else       cA[idx] = (signed char)(cnt - thr0[o]);  // fold threshold in
    return;
  }
  int g2 = gid - 524288;
  if (g2 < 32768) {                // pack mask1: M1p[o][kw]; LSB-first bits
    int kw = g2 >> 10, o = g2 & 1023;
    unsigned wv = 0;
#pragma unroll
    for (int b = 0; b < 32; b++)
      wv |= (unsigned)maskbit(mask1, (kw * 32 + b) * 1024 + o, mode) << b;
    M1p[o * 32 + kw] = wv;
    return;
  }
  int g3 = g2 - 32768;
  if (g3 < 768) {                  // pack mask2: M2p[o][kw]
    int kw = g3 / 24, o = g3 % 24;
    unsigned wv = 0;
    for (int b = 0; b < 32; b++)
      wv |= (unsigned)maskbit(mask2, (kw * 32 + b) * 24 + o, mode) << b;
    M2p[o * 32 + kw] = wv;
  }
}

// Layer-0 evaluate + bit-pack (1 px per block, massively parallel).
__global__ __launch_bounds__(256) void pack_x1(
    const signed char* __restrict__ cA, const unsigned char* __restrict__ cB,
    unsigned* __restrict__ X1p) {
  int t = threadIdx.x;
  int lane = t & 63;
  int q = t >> 6;                  // wave id in block
  int n = blockIdx.x;
  int h = n >> 8, w = n & 255;
  const signed char*   ca = cA + h * 1024;
  const unsigned char* cb = cB + w * 1024;
#pragma unroll
  for (int j = 0; j < 4; j++) {
    int o = q * 256 + j * 64 + lane;
    bool bit = ((int)ca[o] + (int)cb[o]) > 0;          // cA+cB > thr0
    unsigned long long bal = __ballot(bit);
    if (lane == 0) {
      uint2 v; v.x = (unsigned)bal; v.y = (unsigned)(bal >> 32);
      *reinterpret_cast<uint2*>(&X1p[n * 32 + q * 8 + 2 * j]) = v;
    }
  }
}

// Main: L1 popcount-GEMM. Block = 128px x 512out, grid 1024 (4 blocks/CU).
// Core: per-thread 8x8 acc, kq real loop (#pragma unroll 1), VGPR <= 128.
// R10: core xor+bcnt forced to 2 ops/word via BCNT_ACC inline asm.
__global__ __launch_bounds__(256) void main_kernel(
    const uint4* __restrict__ X1p4, const uint4* __restrict__ M1p4,
    const int* __restrict__ thr1, unsigned* __restrict__ X2p) {
  __shared__ uint4 lx4[1024];      // 16 KB  X tile  [row][kq^(row&7)]
  __shared__ uint4 lm4[1024];      // 16 KB  M tile (rewritten per oc)
  int t = threadIdx.x;
  int pb = blockIdx.x >> 1;        // pixel-block 0..511
  int half = blockIdx.x & 1;       // output half
  int n0 = pb << 7;
  int wb = (t >> 6) << 6;          // wave base within a 256-element quarter

  // swizzled source index: element L of the linear LDS tile comes from
  // row = L>>3, kq = (L&7)^(row&7)  ->  src = (L&~7) | ((L&7)^((L>>3)&7))
#pragma unroll
  for (int i = 0; i < 4; i++) {
    int L = t + (i << 8);
    int src = (L & ~7) | ((L & 7) ^ ((L >> 3) & 7));
    stage16(&X1p4[(n0 << 3) + src], &lx4[(i << 8) + wb]);
  }
  {
    int oc = half * 4 + ((0 + (pb & 3)) & 3);
#pragma unroll
    for (int i = 0; i < 4; i++) {
      int L = t + (i << 8);
      int src = (oc << 10) | (L & ~7) | ((L & 7) ^ ((L >> 3) & 7));
      stage16(&M1p4[src], &lm4[(i << 8) + wb]);
    }
  }

  int oc_t = t & 15;               // output-thread 0..15 (owns 8 outs, stride 16)
  int pr_t = t >> 4;               // pixel-thread 0..15 (owns 8 px, stride 16)
  int pgrp = pr_t & 3;             // pixel group within wave
  int sx = pr_t & 7;               // X-tile swizzle key (const per thread)
  int so = oc_t & 7;               // M-tile swizzle key

  __syncthreads();                 // drains vmcnt -> lx4 + first lm4 ready

  for (int oc4 = 0; oc4 < 4; oc4++) {
    int oc = half * 4 + ((oc4 + (pb & 3)) & 3);

    unsigned acc[8][8];
#pragma unroll
    for (int i = 0; i < 8; i++)
#pragma unroll
      for (int j = 0; j < 8; j++) acc[i][j] = 0;

#pragma unroll 1
    for (int kq = 0; kq < 8; kq++) {
      const uint4* xp = &lx4[(pr_t << 3) + (kq ^ sx)];
      const uint4* mp = &lm4[(oc_t << 3) + (kq ^ so)];
      uint4 xv[8];
#pragma unroll
      for (int i = 0; i < 8; i++) xv[i] = xp[i << 7];   // +2048B immediates
      uint4 mvn = mp[0];
#pragma unroll
      for (int j = 0; j < 8; j++) {
        uint4 mv = mvn;
        if (j < 7) mvn = mp[(j + 1) << 7];              // 1-deep prefetch
#pragma unroll
        for (int i = 0; i < 8; i++) {
          unsigned w0 = xv[i].x ^ mv.x;
          unsigned w1 = xv[i].y ^ mv.y;
          unsigned w2 = xv[i].z ^ mv.z;
          unsigned w3 = xv[i].w ^ mv.w;
          BCNT_ACC(acc[i][j], w0);
          BCNT_ACC(acc[i][j], w1);
          BCNT_ACC(acc[i][j], w2);
          BCNT_ACC(acc[i][j], w3);
        }
      }
    }

    __syncthreads();               // all waves done reading lm4

    if (oc4 < 3) {                 // issue next M-tile async; lands during pack
      int ocn = half * 4 + ((oc4 + 1 + (pb & 3)) & 3);
#pragma unroll
      for (int i = 0; i < 4; i++) {
        int L = t + (i << 8);
        int src = (ocn << 10) | (L & ~7) | ((L & 7) ^ ((L >> 3) & 7));
        stage16(&M1p4[src], &lm4[(i << 8) + wb]);
      }
    }

    // threshold + ballot-pack x2 bits -> global X2p (no lm4 access here)
    int limv[8];
#pragma unroll
    for (int j = 0; j < 8; j++)
      limv[j] = 1024 - thr1[(oc << 7) + (j << 4) + oc_t];
#pragma unroll
    for (int i = 0; i < 8; i++) {
      unsigned wacc[4] = {0, 0, 0, 0};
#pragma unroll
      for (int j = 0; j < 8; j++) {
        bool bit = ((int)acc[i][j]) < limv[j];          // 1024-acc > thr1
        unsigned long long bal = __ballot(bit);
        unsigned hw16 = (unsigned)(bal >> (pgrp << 4)) & 0xFFFFu;
        wacc[j >> 1] |= hw16 << ((j & 1) << 4);
      }
      if (oc_t == 0) {
        int n = n0 + pr_t + (i << 4);
        uint4 v; v.x = wacc[0]; v.y = wacc[1]; v.z = wacc[2]; v.w = wacc[3];
        *reinterpret_cast<uint4*>(&X2p[(unsigned)n * 32 + (oc << 2)]) = v;
      }
    }

    __syncthreads();               // drains vmcnt -> next lm4 ready
  }
}

// Layer 2 + epilogue: 256 px/block, one px/thread.
__global__ __launch_bounds__(256) void l2_kernel(
    const uint4* __restrict__ X2p4, const unsigned* __restrict__ M2p,
    const int* __restrict__ thr2, const float* __restrict__ image,
    float* __restrict__ out) {
  __shared__ unsigned lm2[768];
  int t = threadIdx.x;
  for (int r = t; r < 768; r += 256) lm2[r] = M2p[r];
  __syncthreads();
  int n = blockIdx.x * 256 + t;
  uint4 xw[8];
#pragma unroll
  for (int q = 0; q < 8; q++) xw[q] = X2p4[(unsigned)n * 8 + q];
#pragma unroll
  for (int c = 0; c < 3; c++) {
    int val = 0;
#pragma unroll
    for (int b = 0; b < 8; b++) {
      int o = c * 8 + b;
      const unsigned* m = &lm2[o * 32];
      unsigned acc2 = 0;
#pragma unroll
      for (int q = 0; q < 8; q++) {
        acc2 += __popc(xw[q].x ^ m[q * 4 + 0]);
        acc2 += __popc(xw[q].y ^ m[q * 4 + 1]);
        acc2 += __popc(xw[q].z ^ m[q * 4 + 2]);
        acc2 += __popc(xw[q].w ^ m[q * 4 + 3]);
      }
      int bit = ((int)(1024u - acc2)) > thr2[o];
      val |= bit << (7 - b);                            // MSB-first
    }
    out[c * 65536 + n] = (float)val;
    out[196608 + c * 65536 + n] = (float)val - image[c * 65536 + n];
  }
}

extern "C" void kernel_launch(void* const* d_in, const int* in_sizes, int n_in,
                              void* d_out, int out_size, void* d_ws, size_t ws_size,
                              hipStream_t stream) {
  const float*         image = (const float*)d_in[0];
  const unsigned char* mask0 = (const unsigned char*)d_in[1];
  const int*           thr0  = (const int*)d_in[2];
  const unsigned char* mask1 = (const unsigned char*)d_in[3];
  const int*           thr1  = (const int*)d_in[4];
  const unsigned char* mask2 = (const unsigned char*)d_in[5];
  const int*           thr2  = (const int*)d_in[6];
  char* ws = (char*)d_ws;
  unsigned*      X1p = (unsigned*)(ws);
  signed char*   cA  = (signed char*)(ws + WS_CA);
  unsigned char* cB  = (unsigned char*)(ws + WS_CB);
  unsigned*      M1p = (unsigned*)(ws + WS_M1);
  unsigned*      M2p = (unsigned*)(ws + WS_M2);
  unsigned*      X2p = (unsigned*)(ws + WS_X2);
  float* out = (float*)d_out;

  hipLaunchKernelGGL(prep_kernel, dim3(2179), dim3(256), 0, stream,
                     mask0, thr0, mask1, mask2, cA, cB, M1p, M2p);
  hipLaunchKernelGGL(pack_x1, dim3(65536), dim3(256), 0, stream, cA, cB, X1p);
  hipLaunchKernelGGL(main_kernel, dim3(1024), dim3(256), 0, stream,
                     (const uint4*)X1p, (const uint4*)M1p, thr1, X2p);
  hipLaunchKernelGGL(l2_kernel, dim3(256), dim3(256), 0, stream,
                     (const uint4*)X2p, M2p, thr2, image, out);
}